// Round 9
// baseline (404.531 us; speedup 1.0000x reference)
//
#include <hip/hip_runtime.h>

#define N_NODES 100000
#define N_EDGES 3200000
#define D 128

#define MT 64                         // GEMM M-tile rows
#define NTILES 2                      // M-tiles per GEMM block (W staged once)
#define BSPAN 32                      // rows per gather bucket
#define NB 3125                       // N_NODES / BSPAN (exact)
#define CAP 1280                      // records per bucket (mean 1024, +8 sigma)
#define PBLOCKS 256
#define PCHUNK (N_EDGES / PBLOCKS)    // 12500 edges per partition block
#define OVF_CAP 8192

// ws layout (bytes)
#define SUP_OFF     0ULL                               // bf16 support: 25,600,000
#define RECS_OFF    25600000ULL                        // NB*CAP*8 = 32,000,000
#define TAILS_OFF   (RECS_OFF + (size_t)NB * CAP * 8)  // NB ints
#define OVFCNT_OFF  (TAILS_OFF + (size_t)NB * 4)       // 1 int (contiguous)
#define OVF_OFF     ((OVFCNT_OFF + 15) & ~15ULL)
#define WS_NEED     (OVF_OFF + (size_t)OVF_CAP * 12)

typedef short short8 __attribute__((ext_vector_type(8)));
typedef float floatx4 __attribute__((ext_vector_type(4)));
typedef unsigned short ushort8v __attribute__((ext_vector_type(8)));

__device__ inline ushort f2bf(float f) {
  uint u = __float_as_uint(f);
  u += 0x7FFF + ((u >> 16) & 1);   // RNE
  return (ushort)(u >> 16);
}
__device__ inline float bf_lo(uint b) { return __uint_as_float(b << 16); }
__device__ inline float bf_hi(uint b) { return __uint_as_float(b & 0xFFFF0000u); }

#define LSTR 136   // LDS row stride in shorts (16B-aligned, breaks pow2)

// ---------------------------------------------------------------------------
// Fused GEMM+partition, BOTH at 1024 threads (fixes R7's 256-thread
// partition tail). Blocks [0, PBLOCKS): R4-proven 1024-thread partition
// (+NT packed stores). Blocks [PBLOCKS, +782): GEMM; all 16 waves stage
// W/X (4x faster staging, conflicts spread), waves 0-3 do MFMA, barriers
// are wave-uniform (no early exit).
// ---------------------------------------------------------------------------
__global__ __launch_bounds__(1024) void gemm_partition_fused(
    const float* __restrict__ x, const float* __restrict__ W,
    const float* __restrict__ bias, ushort* __restrict__ support, int M,
    const int* __restrict__ erow, const int* __restrict__ ecol,
    const float* __restrict__ eval, int* __restrict__ tails,
    int2* __restrict__ recs, int* __restrict__ ovf_cnt,
    int3* __restrict__ ovf) {
  __shared__ ushort WT[D * LSTR];      // 34816 B; partition reuses as cnt/cursor
  __shared__ ushort XT[MT * LSTR];     // 17408 B

  const int t = threadIdx.x;

  if (blockIdx.x < PBLOCKS) {
    // -------- partition branch: 1024 threads (R4-proven) + NT stores --------
    int* cnt = (int*)WT;        // NB ints = 12.5 KB
    int* cursor = cnt + NB;     // +12.5 KB = 25 KB <= 34.8 KB
    for (int i = t; i < NB; i += 1024) cnt[i] = 0;
    __syncthreads();

    const int e0 = blockIdx.x * PCHUNK;
    for (int e = e0 + t; e < e0 + PCHUNK; e += 1024)
      atomicAdd(&cnt[erow[e] >> 5], 1);
    __syncthreads();

    for (int i = t; i < NB; i += 1024) {
      const int c = cnt[i];
      cursor[i] = (c > 0) ? atomicAdd(&tails[i], c) : 0;
    }
    __syncthreads();

    for (int e = e0 + t; e < e0 + PCHUNK; e += 1024) {
      const int row = erow[e];
      const int b = row >> 5;
      const int pos = atomicAdd(&cursor[b], 1);
      const int col = ecol[e];
      const int vb = __float_as_int(eval[e]);
      if (pos < CAP) {
        const unsigned long long pk =
            (unsigned)(col | ((row & 31) << 20)) |
            ((unsigned long long)(unsigned)vb << 32);
        __builtin_nontemporal_store(
            (long long)pk, (long long*)&recs[(size_t)b * CAP + pos]);
      } else {
        const int oi = atomicAdd(ovf_cnt, 1);
        if (oi < OVF_CAP) ovf[oi] = make_int3(row, col, vb);
      }
    }
    return;
  }

  // -------- GEMM branch: 16 waves stage, waves 0-3 compute --------
  const int w = t >> 6;                 // 0..15
  const int lane = t & 63;
  const int quad = lane >> 4;
  const int l16 = lane & 15;

  // stage W (row-major [k][n] fp32) -> WT[n][k] bf16 (transpose), ONCE
  for (int i = t * 4; i < D * D; i += 4096) {
    const int k = i >> 7, n = i & 127;
    const float4 wv = *(const float4*)&W[i];
    WT[(n + 0) * LSTR + k] = f2bf(wv.x);
    WT[(n + 1) * LSTR + k] = f2bf(wv.y);
    WT[(n + 2) * LSTR + k] = f2bf(wv.z);
    WT[(n + 3) * LSTR + k] = f2bf(wv.w);
  }

  float bs[8];
  if (w < 4) {
#pragma unroll
    for (int nt = 0; nt < 8; nt++) bs[nt] = bias[nt * 16 + l16];
  }

  for (int tile = 0; tile < NTILES; tile++) {
    const int row0 = ((blockIdx.x - PBLOCKS) * NTILES + tile) * MT;
    if (row0 >= M) break;

    // stage x rows -> XT[m][k] bf16 (zero-pad past M); all 1024 threads
    for (int i = t * 4; i < MT * D; i += 4096) {
      const int m = i >> 7, k = i & 127;
      const int r = row0 + m;
      float4 xv = make_float4(0.f, 0.f, 0.f, 0.f);
      if (r < M) xv = *(const float4*)&x[(size_t)r * D + k];
      ushort4 pv;
      pv.x = f2bf(xv.x); pv.y = f2bf(xv.y); pv.z = f2bf(xv.z); pv.w = f2bf(xv.w);
      *(ushort4*)&XT[m * LSTR + k] = pv;
    }
    __syncthreads();

    floatx4 acc[8];
    if (w < 4) {
#pragma unroll
      for (int nt = 0; nt < 8; nt++) acc[nt] = (floatx4)0.f;
#pragma unroll
      for (int kc = 0; kc < 4; kc++) {
        const short8 a = *(const short8*)&XT[(w * 16 + l16) * LSTR + kc * 32 + quad * 8];
#pragma unroll
        for (int nt = 0; nt < 8; nt++) {
          const short8 b = *(const short8*)&WT[(nt * 16 + l16) * LSTR + kc * 32 + quad * 8];
          acc[nt] = __builtin_amdgcn_mfma_f32_16x16x32_bf16(a, b, acc[nt], 0, 0, 0);
        }
      }
    }
    __syncthreads();  // all XT reads done before repack overwrites

    if (w < 4) {
      // repack D into XT (row-major, stride LSTR) for coalesced writeout
#pragma unroll
      for (int nt = 0; nt < 8; nt++)
#pragma unroll
        for (int r = 0; r < 4; r++)
          XT[(w * 16 + quad * 4 + r) * LSTR + nt * 16 + l16] = f2bf(acc[nt][r] + bs[nt]);
    }
    __syncthreads();

    // writeout by all 1024 threads: 8192 shorts, one ushort8 each
    {
      const int i = t * 8;
      const int m = i >> 7, k = i & 127;
      const int r = row0 + m;
      if (i < MT * D && r < M)
        *(ushort8v*)&support[(size_t)r * D + k] = *(const ushort8v*)&XT[m * LSTR + k];
    }
    __syncthreads();  // XT free for next tile
  }
}

// Standalone GEMM (fallback path only).
__global__ __launch_bounds__(256) void gcn_gemm_mfma(
    const float* __restrict__ x, const float* __restrict__ W,
    const float* __restrict__ bias, ushort* __restrict__ support, int M) {
  __shared__ ushort WT[D * LSTR];
  __shared__ ushort XT[MT * LSTR];

  const int t = threadIdx.x;
  const int w = t >> 6;
  const int lane = t & 63;
  const int quad = lane >> 4;
  const int l16 = lane & 15;
  const int row0 = blockIdx.x * MT;

  for (int i = t * 4; i < D * D; i += 1024) {
    const int k = i >> 7, n = i & 127;
    const float4 wv = *(const float4*)&W[i];
    WT[(n + 0) * LSTR + k] = f2bf(wv.x);
    WT[(n + 1) * LSTR + k] = f2bf(wv.y);
    WT[(n + 2) * LSTR + k] = f2bf(wv.z);
    WT[(n + 3) * LSTR + k] = f2bf(wv.w);
  }
  for (int i = t * 4; i < MT * D; i += 1024) {
    const int m = i >> 7, k = i & 127;
    const int r = row0 + m;
    float4 xv = make_float4(0.f, 0.f, 0.f, 0.f);
    if (r < M) xv = *(const float4*)&x[(size_t)r * D + k];
    ushort4 pv;
    pv.x = f2bf(xv.x); pv.y = f2bf(xv.y); pv.z = f2bf(xv.z); pv.w = f2bf(xv.w);
    *(ushort4*)&XT[m * LSTR + k] = pv;
  }
  __syncthreads();

  floatx4 acc[8];
#pragma unroll
  for (int nt = 0; nt < 8; nt++) acc[nt] = (floatx4)0.f;

#pragma unroll
  for (int kc = 0; kc < 4; kc++) {
    const short8 a = *(const short8*)&XT[(w * 16 + l16) * LSTR + kc * 32 + quad * 8];
#pragma unroll
    for (int nt = 0; nt < 8; nt++) {
      const short8 b = *(const short8*)&WT[(nt * 16 + l16) * LSTR + kc * 32 + quad * 8];
      acc[nt] = __builtin_amdgcn_mfma_f32_16x16x32_bf16(a, b, acc[nt], 0, 0, 0);
    }
  }

  float bs[8];
#pragma unroll
  for (int nt = 0; nt < 8; nt++) bs[nt] = bias[nt * 16 + l16];

  __syncthreads();
#pragma unroll
  for (int nt = 0; nt < 8; nt++)
#pragma unroll
    for (int r = 0; r < 4; r++)
      XT[(w * 16 + quad * 4 + r) * LSTR + nt * 16 + l16] = f2bf(acc[nt][r] + bs[nt]);
  __syncthreads();

  for (int i = t * 8; i < MT * D; i += 2048) {
    const int m = i >> 7, k = i & 127;
    const int r = row0 + m;
    if (r < M)
      *(ushort8v*)&support[(size_t)r * D + k] = *(const ushort8v*)&XT[m * LSTR + k];
  }
}

// ---------------------------------------------------------------------------
// Fused bin+gather (R4/R8 proven, ~123 us): block = one 32-row bucket.
// ---------------------------------------------------------------------------
__global__ __launch_bounds__(256, 8) void bucket_gather(
    const ushort* __restrict__ sup, const int* __restrict__ tails,
    const int2* __restrict__ recs, float* __restrict__ out) {
  __shared__ int2 lrec[CAP];            // 10 KB
  __shared__ int rcnt[BSPAN];
  __shared__ int rstart[BSPAN];
  __shared__ int rend[BSPAN];
  __shared__ int rpos[BSPAN];

  const int bi = blockIdx.x;
  const int t = threadIdx.x;
  const int n = min(tails[bi], CAP);
  const long long* __restrict__ gb64 =
      (const long long*)(recs + (size_t)bi * CAP);

  if (t < BSPAN) rcnt[t] = 0;
  __syncthreads();

  int2 rcache[5];
  int nr = 0;
  for (int i = t; i < n; i += 256) {
    const long long v = __builtin_nontemporal_load(&gb64[i]);
    rcache[nr++] = make_int2((int)(unsigned long long)v, (int)(v >> 32));
  }

  for (int j = 0; j < nr; j++) atomicAdd(&rcnt[rcache[j].x >> 20], 1);
  __syncthreads();

  if (t < BSPAN) {
    const int c = rcnt[t];
    int v = c;
#pragma unroll
    for (int off = 1; off < BSPAN; off <<= 1) {
      const int u = __shfl_up(v, off);
      if (t >= off) v += u;
    }
    rend[t] = v;
    rstart[t] = v - c;
    rpos[t] = v - c;
  }
  __syncthreads();

  for (int j = 0; j < nr; j++) {
    const int2 rc = rcache[j];
    const int p = atomicAdd(&rpos[rc.x >> 20], 1);
    lrec[p] = make_int2((rc.x & 0xFFFFF) << 8, rc.y);  // byte offset into sup
  }
  __syncthreads();

  const int lane = t & 63;
  const int w = t >> 6;
  const int g = lane >> 4;
  const int gl = lane & 15;
  const char* __restrict__ supb = (const char*)sup;

  for (int j = 0; j < 8; j++) {
    const int rr = w * 8 + j;
    const int s = rstart[rr];
    const int e = rend[rr];
    float4 acc0 = make_float4(0.f, 0.f, 0.f, 0.f);
    float4 acc1 = make_float4(0.f, 0.f, 0.f, 0.f);
    for (int i = s; i < e; i += 16) {
      int coff[4];
      float val[4];
      uint4 b[4];
#pragma unroll
      for (int sl = 0; sl < 4; sl++) {
        const int idx = i + sl * 4 + g;
        const int2 rc = lrec[min(idx, CAP - 1)];
        const bool valid = idx < e;
        coff[sl] = valid ? rc.x : 0;
        val[sl] = valid ? __int_as_float(rc.y) : 0.f;
      }
#pragma unroll
      for (int sl = 0; sl < 4; sl++)
        b[sl] = *(const uint4*)(supb + coff[sl] + gl * 16);
#pragma unroll
      for (int sl = 0; sl < 4; sl++) {
        acc0.x += val[sl] * bf_lo(b[sl].x);
        acc0.y += val[sl] * bf_hi(b[sl].x);
        acc0.z += val[sl] * bf_lo(b[sl].y);
        acc0.w += val[sl] * bf_hi(b[sl].y);
        acc1.x += val[sl] * bf_lo(b[sl].z);
        acc1.y += val[sl] * bf_hi(b[sl].z);
        acc1.z += val[sl] * bf_lo(b[sl].w);
        acc1.w += val[sl] * bf_hi(b[sl].w);
      }
    }
#pragma unroll
    for (int off = 16; off <= 32; off <<= 1) {
      acc0.x += __shfl_xor(acc0.x, off);
      acc0.y += __shfl_xor(acc0.y, off);
      acc0.z += __shfl_xor(acc0.z, off);
      acc0.w += __shfl_xor(acc0.w, off);
      acc1.x += __shfl_xor(acc1.x, off);
      acc1.y += __shfl_xor(acc1.y, off);
      acc1.z += __shfl_xor(acc1.z, off);
      acc1.w += __shfl_xor(acc1.w, off);
    }
    const int row = bi * BSPAN + rr;
    if (g == 0 && row < N_NODES) {
      float* op = &out[(size_t)row * D + gl * 8];
      __builtin_nontemporal_store(acc0.x, op + 0);
      __builtin_nontemporal_store(acc0.y, op + 1);
      __builtin_nontemporal_store(acc0.z, op + 2);
      __builtin_nontemporal_store(acc0.w, op + 3);
      __builtin_nontemporal_store(acc1.x, op + 4);
      __builtin_nontemporal_store(acc1.y, op + 5);
      __builtin_nontemporal_store(acc1.z, op + 6);
      __builtin_nontemporal_store(acc1.w, op + 7);
    }
  }
}

// Overflow apply (expected n == 0; safety net). Grid-stride, 128 blocks.
__global__ __launch_bounds__(256) void ovf_apply(
    const int* __restrict__ ovf_cnt, const int3* __restrict__ ovf,
    const ushort* __restrict__ sup, float* __restrict__ out) {
  const int n = min(*ovf_cnt, OVF_CAP);
  for (int tid = blockIdx.x * 256 + threadIdx.x; tid < n * 32;
       tid += 128 * 256) {
    const int e = tid >> 5;
    const int3 rec = ovf[e];
    const float val = __int_as_float(rec.z);
    const int j = (tid & 31) * 4;
#pragma unroll
    for (int k = 0; k < 4; k++) {
      const float f = __uint_as_float(((uint)sup[(size_t)rec.y * D + j + k]) << 16);
      unsafeAtomicAdd(&out[(size_t)rec.x * D + j + k], val * f);
    }
  }
}

// Fallback (atomic path, bf16 support) if ws is too small.
__global__ __launch_bounds__(256) void gcn_spmm_atomic(
    const ushort* __restrict__ sup, const float* __restrict__ edge_val,
    const int* __restrict__ edge_row, const int* __restrict__ edge_col,
    float* __restrict__ out) {
  const long long tid = (long long)blockIdx.x * blockDim.x + threadIdx.x;
  const int e = (int)(tid >> 5);
  if (e >= N_EDGES) return;
  const int j = ((int)tid & 31) * 4;
  const int col = edge_col[e];
  const int row = edge_row[e];
  const float val = edge_val[e];
#pragma unroll
  for (int k = 0; k < 4; k++) {
    const float f = __uint_as_float(((uint)sup[(size_t)col * D + j + k]) << 16);
    unsafeAtomicAdd(&out[(size_t)row * D + j + k], val * f);
  }
}

extern "C" void kernel_launch(void* const* d_in, const int* in_sizes, int n_in,
                              void* d_out, int out_size, void* d_ws,
                              size_t ws_size, hipStream_t stream) {
  const float* x        = (const float*)d_in[0];
  const float* edge_val = (const float*)d_in[1];
  const float* W        = (const float*)d_in[2];
  const float* bias     = (const float*)d_in[3];
  const int*   edge_row = (const int*)d_in[4];
  const int*   edge_col = (const int*)d_in[5];
  float* out = (float*)d_out;

  char* ws = (char*)d_ws;
  ushort* support = (ushort*)(ws + SUP_OFF);

  if (ws_size >= WS_NEED) {
    int2* recs   = (int2*)(ws + RECS_OFF);
    int*  tails  = (int*)(ws + TAILS_OFF);
    int*  ovfcnt = (int*)(ws + OVFCNT_OFF);
    int3* ovf    = (int3*)(ws + OVF_OFF);

    const int gemm_blocks = (N_NODES + MT * NTILES - 1) / (MT * NTILES);
    hipMemsetAsync(tails, 0, (size_t)NB * 4 + 4, stream);
    gemm_partition_fused<<<PBLOCKS + gemm_blocks, 1024, 0, stream>>>(
        x, W, bias, support, N_NODES,
        edge_row, edge_col, edge_val, tails, recs, ovfcnt, ovf);
    bucket_gather<<<NB, 256, 0, stream>>>(support, tails, recs, out);
    ovf_apply<<<128, 256, 0, stream>>>(ovfcnt, ovf, support, out);
  } else {
    const int gemm_blocks = (N_NODES + MT - 1) / MT;
    gcn_gemm_mfma<<<gemm_blocks, 256, 0, stream>>>(x, W, bias, support, N_NODES);
    hipMemsetAsync(out, 0, (size_t)out_size * sizeof(float), stream);
    const long long spmm_threads = (long long)N_EDGES * 32;
    gcn_spmm_atomic<<<(int)((spmm_threads + 255) / 256), 256, 0, stream>>>(
        support, edge_val, edge_row, edge_col, out);
  }
}

// Round 10
// 357.677 us; speedup vs baseline: 1.1310x; 1.1310x over previous
//
#include <hip/hip_runtime.h>

#define N_NODES 100000
#define N_EDGES 3200000
#define D 128

#define MT 64                         // GEMM M-tile rows
#define NTILES 2                      // M-tiles per GEMM block (W staged once)
#define BSPAN 32                      // rows per gather bucket
#define NB 3125                       // N_NODES / BSPAN (exact)
#define CAP 1280                      // records per bucket (mean 1024, +8 sigma)
#define PBLOCKS 256
#define PCHUNK (N_EDGES / PBLOCKS)    // 12500 edges per partition block
#define OVF_CAP 8192

// ws layout (bytes)
#define SUP_OFF     0ULL                               // bf16 support: 25,600,000
#define RECS_OFF    25600000ULL                        // NB*CAP*8 = 32,000,000
#define TAILS_OFF   (RECS_OFF + (size_t)NB * CAP * 8)  // NB ints
#define OVFCNT_OFF  (TAILS_OFF + (size_t)NB * 4)       // 1 int (contiguous)
#define OVF_OFF     ((OVFCNT_OFF + 15) & ~15ULL)
#define WS_NEED     (OVF_OFF + (size_t)OVF_CAP * 12)

typedef short short8 __attribute__((ext_vector_type(8)));
typedef float floatx4 __attribute__((ext_vector_type(4)));
typedef unsigned short ushort8v __attribute__((ext_vector_type(8)));

__device__ inline ushort f2bf(float f) {
  uint u = __float_as_uint(f);
  u += 0x7FFF + ((u >> 16) & 1);   // RNE
  return (ushort)(u >> 16);
}
__device__ inline float bf_lo(uint b) { return __uint_as_float(b << 16); }
__device__ inline float bf_hi(uint b) { return __uint_as_float(b & 0xFFFF0000u); }

#define LSTR 136   // LDS row stride in shorts (16B-aligned, breaks pow2)

// ---------------------------------------------------------------------------
// Kernel A: support(bf16) = x @ W + bias via MFMA 16x16x32 bf16.
// Block = 256 thr = 4 waves; NTILES 64-row M-tiles per block; W transposed
// to LDS once per block (16-way-conflict transpose amortized over NTILES).
// ---------------------------------------------------------------------------
__global__ __launch_bounds__(256) void gcn_gemm_mfma(
    const float* __restrict__ x, const float* __restrict__ W,
    const float* __restrict__ bias, ushort* __restrict__ support, int M) {
  __shared__ ushort WT[D * LSTR];      // 34816 B, WT[n][k]
  __shared__ ushort XT[MT * LSTR];     // 17408 B, XT[m][k]; reused for repack

  const int t = threadIdx.x;
  const int w = t >> 6;
  const int lane = t & 63;
  const int quad = lane >> 4;
  const int l16 = lane & 15;

  // stage W (row-major [k][n] fp32) -> WT[n][k] bf16 (transpose), ONCE
  for (int i = t * 4; i < D * D; i += 1024) {
    const int k = i >> 7, n = i & 127;
    const float4 wv = *(const float4*)&W[i];
    WT[(n + 0) * LSTR + k] = f2bf(wv.x);
    WT[(n + 1) * LSTR + k] = f2bf(wv.y);
    WT[(n + 2) * LSTR + k] = f2bf(wv.z);
    WT[(n + 3) * LSTR + k] = f2bf(wv.w);
  }

  float bs[8];
#pragma unroll
  for (int nt = 0; nt < 8; nt++) bs[nt] = bias[nt * 16 + l16];

  for (int tile = 0; tile < NTILES; tile++) {
    const int row0 = (blockIdx.x * NTILES + tile) * MT;
    if (row0 >= M) break;

    // stage x rows -> XT[m][k] bf16 (zero-pad past M)
    for (int i = t * 4; i < MT * D; i += 1024) {
      const int m = i >> 7, k = i & 127;
      const int r = row0 + m;
      float4 xv = make_float4(0.f, 0.f, 0.f, 0.f);
      if (r < M) xv = *(const float4*)&x[(size_t)r * D + k];
      ushort4 pv;
      pv.x = f2bf(xv.x); pv.y = f2bf(xv.y); pv.z = f2bf(xv.z); pv.w = f2bf(xv.w);
      *(ushort4*)&XT[m * LSTR + k] = pv;
    }
    __syncthreads();

    floatx4 acc[8];
#pragma unroll
    for (int nt = 0; nt < 8; nt++) acc[nt] = (floatx4)0.f;

#pragma unroll
    for (int kc = 0; kc < 4; kc++) {
      const short8 a = *(const short8*)&XT[(w * 16 + l16) * LSTR + kc * 32 + quad * 8];
#pragma unroll
      for (int nt = 0; nt < 8; nt++) {
        const short8 b = *(const short8*)&WT[(nt * 16 + l16) * LSTR + kc * 32 + quad * 8];
        acc[nt] = __builtin_amdgcn_mfma_f32_16x16x32_bf16(a, b, acc[nt], 0, 0, 0);
      }
    }

    __syncthreads();  // done reading XT as input tile
    // repack D into XT (row-major, stride LSTR) for coalesced writeout
#pragma unroll
    for (int nt = 0; nt < 8; nt++)
#pragma unroll
      for (int r = 0; r < 4; r++)
        XT[(w * 16 + quad * 4 + r) * LSTR + nt * 16 + l16] = f2bf(acc[nt][r] + bs[nt]);
    __syncthreads();

    for (int i = t * 8; i < MT * D; i += 2048) {
      const int m = i >> 7, k = i & 127;
      const int r = row0 + m;
      if (r < M)
        *(ushort8v*)&support[(size_t)r * D + k] = *(const ushort8v*)&XT[m * LSTR + k];
    }
    __syncthreads();  // XT free for next tile
  }
}

// ---------------------------------------------------------------------------
// Partition (R4-proven config): 1024 threads, block-local binning ->
// contiguous per-block runs in row buckets.
// ---------------------------------------------------------------------------
__global__ __launch_bounds__(1024) void partition_kernel(
    const int* __restrict__ erow, const int* __restrict__ ecol,
    const float* __restrict__ eval, int* __restrict__ tails,
    int2* __restrict__ recs, int* __restrict__ ovf_cnt,
    int3* __restrict__ ovf) {
  __shared__ int cnt[NB];
  __shared__ int cursor[NB];
  const int t = threadIdx.x;
  for (int i = t; i < NB; i += 1024) cnt[i] = 0;
  __syncthreads();

  const int e0 = blockIdx.x * PCHUNK;
  for (int e = e0 + t; e < e0 + PCHUNK; e += 1024)
    atomicAdd(&cnt[erow[e] >> 5], 1);
  __syncthreads();

  for (int i = t; i < NB; i += 1024) {
    const int c = cnt[i];
    cursor[i] = (c > 0) ? atomicAdd(&tails[i], c) : 0;
  }
  __syncthreads();

  for (int e = e0 + t; e < e0 + PCHUNK; e += 1024) {
    const int row = erow[e];
    const int b = row >> 5;
    const int pos = atomicAdd(&cursor[b], 1);
    const int col = ecol[e];
    const int vb = __float_as_int(eval[e]);
    if (pos < CAP) {
      recs[(size_t)b * CAP + pos] = make_int2(col | ((row & 31) << 20), vb);
    } else {
      const int oi = atomicAdd(ovf_cnt, 1);
      if (oi < OVF_CAP) ovf[oi] = make_int3(row, col, vb);
    }
  }
}

// ---------------------------------------------------------------------------
// Fused bin+gather (R4/R8 proven, ~123 us): block = one 32-row bucket.
//  wave w owns rows w*8..+7; QUARTER-WAVE per record, 4-slot pipeline
//  (4x dwordx4 in flight); shfl_xor(16|32) combine; NT writeout.
//  Overflow records (expected none) folded in before writeout — removes
//  the separate ovf_apply dispatch.
// ---------------------------------------------------------------------------
__global__ __launch_bounds__(256, 8) void bucket_gather(
    const ushort* __restrict__ sup, const int* __restrict__ tails,
    const int2* __restrict__ recs, const int* __restrict__ ovf_cnt,
    const int3* __restrict__ ovf, float* __restrict__ out) {
  __shared__ int2 lrec[CAP];            // 10 KB
  __shared__ int rcnt[BSPAN];
  __shared__ int rstart[BSPAN];
  __shared__ int rend[BSPAN];
  __shared__ int rpos[BSPAN];

  const int bi = blockIdx.x;
  const int t = threadIdx.x;
  const int n = min(tails[bi], CAP);
  const int novf = min(*ovf_cnt, OVF_CAP);
  const long long* __restrict__ gb64 =
      (const long long*)(recs + (size_t)bi * CAP);

  if (t < BSPAN) rcnt[t] = 0;
  __syncthreads();

  int2 rcache[5];
  int nr = 0;
  for (int i = t; i < n; i += 256) {
    const long long v = __builtin_nontemporal_load(&gb64[i]);
    rcache[nr++] = make_int2((int)(unsigned long long)v, (int)(v >> 32));
  }

  for (int j = 0; j < nr; j++) atomicAdd(&rcnt[rcache[j].x >> 20], 1);
  __syncthreads();

  if (t < BSPAN) {
    const int c = rcnt[t];
    int v = c;
#pragma unroll
    for (int off = 1; off < BSPAN; off <<= 1) {
      const int u = __shfl_up(v, off);
      if (t >= off) v += u;
    }
    rend[t] = v;
    rstart[t] = v - c;
    rpos[t] = v - c;
  }
  __syncthreads();

  for (int j = 0; j < nr; j++) {
    const int2 rc = rcache[j];
    const int p = atomicAdd(&rpos[rc.x >> 20], 1);
    lrec[p] = make_int2((rc.x & 0xFFFFF) << 8, rc.y);  // byte offset into sup
  }
  __syncthreads();

  const int lane = t & 63;
  const int w = t >> 6;
  const int g = lane >> 4;
  const int gl = lane & 15;
  const char* __restrict__ supb = (const char*)sup;

  for (int j = 0; j < 8; j++) {
    const int rr = w * 8 + j;
    const int s = rstart[rr];
    const int e = rend[rr];
    float4 acc0 = make_float4(0.f, 0.f, 0.f, 0.f);
    float4 acc1 = make_float4(0.f, 0.f, 0.f, 0.f);
    for (int i = s; i < e; i += 16) {
      int coff[4];
      float val[4];
      uint4 b[4];
#pragma unroll
      for (int sl = 0; sl < 4; sl++) {
        const int idx = i + sl * 4 + g;
        const int2 rc = lrec[min(idx, CAP - 1)];
        const bool valid = idx < e;
        coff[sl] = valid ? rc.x : 0;
        val[sl] = valid ? __int_as_float(rc.y) : 0.f;
      }
#pragma unroll
      for (int sl = 0; sl < 4; sl++)
        b[sl] = *(const uint4*)(supb + coff[sl] + gl * 16);
#pragma unroll
      for (int sl = 0; sl < 4; sl++) {
        acc0.x += val[sl] * bf_lo(b[sl].x);
        acc0.y += val[sl] * bf_hi(b[sl].x);
        acc0.z += val[sl] * bf_lo(b[sl].y);
        acc0.w += val[sl] * bf_hi(b[sl].y);
        acc1.x += val[sl] * bf_lo(b[sl].z);
        acc1.y += val[sl] * bf_hi(b[sl].z);
        acc1.z += val[sl] * bf_lo(b[sl].w);
        acc1.w += val[sl] * bf_hi(b[sl].w);
      }
    }
#pragma unroll
    for (int off = 16; off <= 32; off <<= 1) {
      acc0.x += __shfl_xor(acc0.x, off);
      acc0.y += __shfl_xor(acc0.y, off);
      acc0.z += __shfl_xor(acc0.z, off);
      acc0.w += __shfl_xor(acc0.w, off);
      acc1.x += __shfl_xor(acc1.x, off);
      acc1.y += __shfl_xor(acc1.y, off);
      acc1.z += __shfl_xor(acc1.z, off);
      acc1.w += __shfl_xor(acc1.w, off);
    }
    const int row = bi * BSPAN + rr;
    if (g == 0 && row < N_NODES) {
      // fold any overflow records for this row (novf expected 0)
      for (int oi = 0; oi < novf; oi++) {
        const int3 rec = ovf[oi];
        if (rec.x == row) {
          const float v = __int_as_float(rec.z);
          const uint4 b = *(const uint4*)(supb + (((size_t)rec.y) << 8) + gl * 16);
          acc0.x += v * bf_lo(b.x);
          acc0.y += v * bf_hi(b.x);
          acc0.z += v * bf_lo(b.y);
          acc0.w += v * bf_hi(b.y);
          acc1.x += v * bf_lo(b.z);
          acc1.y += v * bf_hi(b.z);
          acc1.z += v * bf_lo(b.w);
          acc1.w += v * bf_hi(b.w);
        }
      }
      float* op = &out[(size_t)row * D + gl * 8];
      __builtin_nontemporal_store(acc0.x, op + 0);
      __builtin_nontemporal_store(acc0.y, op + 1);
      __builtin_nontemporal_store(acc0.z, op + 2);
      __builtin_nontemporal_store(acc0.w, op + 3);
      __builtin_nontemporal_store(acc1.x, op + 4);
      __builtin_nontemporal_store(acc1.y, op + 5);
      __builtin_nontemporal_store(acc1.z, op + 6);
      __builtin_nontemporal_store(acc1.w, op + 7);
    }
  }
}

// Fallback (atomic path, bf16 support) if ws is too small.
__global__ __launch_bounds__(256) void gcn_spmm_atomic(
    const ushort* __restrict__ sup, const float* __restrict__ edge_val,
    const int* __restrict__ edge_row, const int* __restrict__ edge_col,
    float* __restrict__ out) {
  const long long tid = (long long)blockIdx.x * blockDim.x + threadIdx.x;
  const int e = (int)(tid >> 5);
  if (e >= N_EDGES) return;
  const int j = ((int)tid & 31) * 4;
  const int col = edge_col[e];
  const int row = edge_row[e];
  const float val = edge_val[e];
#pragma unroll
  for (int k = 0; k < 4; k++) {
    const float f = __uint_as_float(((uint)sup[(size_t)col * D + j + k]) << 16);
    unsafeAtomicAdd(&out[(size_t)row * D + j + k], val * f);
  }
}

extern "C" void kernel_launch(void* const* d_in, const int* in_sizes, int n_in,
                              void* d_out, int out_size, void* d_ws,
                              size_t ws_size, hipStream_t stream) {
  const float* x        = (const float*)d_in[0];
  const float* edge_val = (const float*)d_in[1];
  const float* W        = (const float*)d_in[2];
  const float* bias     = (const float*)d_in[3];
  const int*   edge_row = (const int*)d_in[4];
  const int*   edge_col = (const int*)d_in[5];
  float* out = (float*)d_out;

  char* ws = (char*)d_ws;
  ushort* support = (ushort*)(ws + SUP_OFF);

  const int gemm_blocks = (N_NODES + MT * NTILES - 1) / (MT * NTILES);
  gcn_gemm_mfma<<<gemm_blocks, 256, 0, stream>>>(x, W, bias, support, N_NODES);

  if (ws_size >= WS_NEED) {
    int2* recs   = (int2*)(ws + RECS_OFF);
    int*  tails  = (int*)(ws + TAILS_OFF);
    int*  ovfcnt = (int*)(ws + OVFCNT_OFF);
    int3* ovf    = (int3*)(ws + OVF_OFF);

    hipMemsetAsync(tails, 0, (size_t)NB * 4 + 4, stream);
    partition_kernel<<<PBLOCKS, 1024, 0, stream>>>(edge_row, edge_col, edge_val,
                                                   tails, recs, ovfcnt, ovf);
    bucket_gather<<<NB, 256, 0, stream>>>(support, tails, recs, ovfcnt, ovf, out);
  } else {
    hipMemsetAsync(out, 0, (size_t)out_size * sizeof(float), stream);
    const long long spmm_threads = (long long)N_EDGES * 32;
    gcn_spmm_atomic<<<(int)((spmm_threads + 255) / 256), 256, 0, stream>>>(
        support, edge_val, edge_row, edge_col, out);
  }
}